// Round 3
// baseline (207.050 us; speedup 1.0000x reference)
//
#include <hip/hip_runtime.h>
#include <hip/hip_bf16.h>

#define S_LEN 2048
#define D_DIM 64
#define NQB   16                                // S / 128 q-blocks
#define KVB   64
#define QS    (0.125f * 1.44269504088896341f)   // 1/sqrt(64) * log2(e): softmax in base-2

using f32x4  = __attribute__((ext_vector_type(4))) float;
using bf16x8 = __attribute__((ext_vector_type(8))) short;   // 8 bf16 (guide-verified fragment type)

__device__ __forceinline__ unsigned short f2bf(float f) {
    return __builtin_bit_cast(unsigned short, __float2bfloat16(f));   // HW RNE cvt
}
__device__ __forceinline__ unsigned pk2bf(float lo, float hi) {
    return (unsigned)f2bf(lo) | ((unsigned)f2bf(hi) << 16);
}
// ushort-index swizzle for [r][64]-bf16 tiles: spreads row-stride-128B across 8 16B slots
__device__ __forceinline__ int swz(int r, int c) {
    return (r * 64 + c) ^ ((r & 7) << 3);
}

// LDS map (ushort units): buf0 K@0 V@4096 | buf1 K@8192 V@12288 | P@16384 (1024/wave)
__global__ __launch_bounds__(256)
void attn_fwd(const float* __restrict__ Qg, const float* __restrict__ Kg,
              const float* __restrict__ Vg, float* __restrict__ Og) {
    __shared__ __align__(16) unsigned short lds[20480];   // 40 KB

    const int wg  = blockIdx.x;
    const int cid = (wg & 7) * 64 + (wg >> 3);   // T1 XCD chunk swizzle (bijective: 512%8==0)
    const int bh  = cid >> 4;                    // 4 bh per XCD -> 4MB L2 working set
    const int QB  = (NQB - 1) - (cid & 15);      // heavy q-blocks first

    const int tid  = threadIdx.x;
    const int wid  = tid >> 6;
    const int lane = tid & 63;
    const int lo   = lane & 15;
    const int hi   = lane >> 4;

    const size_t boff = (size_t)bh * (S_LEN * D_DIM);
    const float* Qp = Qg + boff;
    const float* Kp = Kg + boff;
    const float* Vp = Vg + boff;
    float*       Op = Og + boff;

    const int qrow0 = QB * 128 + wid * 32;   // wave owns 32 q-rows = 2 strips of 16

    // ---- Q fragments in registers for whole kernel, pre-scaled (scale folded before
    // bf16 round; consistent across softmax so invariant to the base change)
    bf16x8 qf[2][2];
    #pragma unroll
    for (int s = 0; s < 2; ++s)
        #pragma unroll
        for (int kc = 0; kc < 2; ++kc) {
            const float* src = Qp + (size_t)(qrow0 + s * 16 + lo) * D_DIM + kc * 32 + hi * 8;
            f32x4 a = *(const f32x4*)src;
            f32x4 b = *(const f32x4*)(src + 4);
            union { bf16x8 v; unsigned u[4]; } fr;
            fr.u[0] = pk2bf(a[0] * QS, a[1] * QS);
            fr.u[1] = pk2bf(a[2] * QS, a[3] * QS);
            fr.u[2] = pk2bf(b[0] * QS, b[1] * QS);
            fr.u[3] = pk2bf(b[2] * QS, b[3] * QS);
            qf[s][kc] = fr.v;
        }

    float mrow[2][4], lrow[2][4];
    f32x4 oacc[2][4];
    #pragma unroll
    for (int s = 0; s < 2; ++s)
        #pragma unroll
        for (int r = 0; r < 4; ++r) { mrow[s][r] = -INFINITY; lrow[s][r] = 0.f; }
    #pragma unroll
    for (int s = 0; s < 2; ++s)
        #pragma unroll
        for (int dn = 0; dn < 4; ++dn) oacc[s][dn] = f32x4{0.f, 0.f, 0.f, 0.f};

    // staging geometry: K: thread = 1 row x 16 cols; V: 2 adjacent rows x 8 cols (-> b32 V^T writes)
    const int kr    = tid >> 2;
    const int kcb   = (tid & 3) << 4;
    const int vr    = (tid & 31) << 1;
    const int vcb   = (tid >> 5) << 3;
    const int pbase = 16384 + (wid << 10);

    const int T = 2 * QB + 2;
    f32x4 kst[4], vst[4];

    // prologue: load + stage tile 0 into buffer 0
    {
        const float* ks = Kp + (size_t)kr * D_DIM + kcb;
        kst[0] = *(const f32x4*)ks;       kst[1] = *(const f32x4*)(ks + 4);
        kst[2] = *(const f32x4*)(ks + 8); kst[3] = *(const f32x4*)(ks + 12);
        const float* vs = Vp + (size_t)vr * D_DIM + vcb;
        vst[0] = *(const f32x4*)vs;           vst[1] = *(const f32x4*)(vs + 4);
        vst[2] = *(const f32x4*)(vs + D_DIM); vst[3] = *(const f32x4*)(vs + D_DIM + 4);
        union { uint4 q; unsigned u[4]; } w;
        w.u[0] = pk2bf(kst[0][0], kst[0][1]); w.u[1] = pk2bf(kst[0][2], kst[0][3]);
        w.u[2] = pk2bf(kst[1][0], kst[1][1]); w.u[3] = pk2bf(kst[1][2], kst[1][3]);
        *(uint4*)&lds[swz(kr, kcb)] = w.q;
        w.u[0] = pk2bf(kst[2][0], kst[2][1]); w.u[1] = pk2bf(kst[2][2], kst[2][3]);
        w.u[2] = pk2bf(kst[3][0], kst[3][1]); w.u[3] = pk2bf(kst[3][2], kst[3][3]);
        *(uint4*)&lds[swz(kr, kcb + 8)] = w.q;
        #pragma unroll
        for (int c = 0; c < 8; ++c) {
            unsigned pv = pk2bf(vst[c >> 2][c & 3], vst[2 + (c >> 2)][c & 3]);
            *(unsigned*)&lds[4096 + swz(vcb + c, vr)] = pv;
        }
    }
    __syncthreads();

    for (int t = 0; t < T; ++t) {
        const int kb = t * KVB;
        const int kA = (t & 1) << 13;
        const int vA = kA + 4096;
        const bool pf = (t + 1 < T);

        // T14: issue next tile's global loads BEFORE compute (latency hides under MFMA/softmax)
        if (pf) {
            const int nb = kb + KVB;
            const float* ks = Kp + (size_t)(nb + kr) * D_DIM + kcb;
            kst[0] = *(const f32x4*)ks;       kst[1] = *(const f32x4*)(ks + 4);
            kst[2] = *(const f32x4*)(ks + 8); kst[3] = *(const f32x4*)(ks + 12);
            const float* vs = Vp + (size_t)(nb + vr) * D_DIM + vcb;
            vst[0] = *(const f32x4*)vs;           vst[1] = *(const f32x4*)(vs + 4);
            vst[2] = *(const f32x4*)(vs + D_DIM); vst[3] = *(const f32x4*)(vs + D_DIM + 4);
        }

        #pragma unroll
        for (int s = 0; s < 2; ++s) {
            const int r0 = qrow0 + s * 16;
            if (kb > r0 + 15) continue;   // strip fully masked (wave-uniform)

            // QK^T
            f32x4 sc[4];
            #pragma unroll
            for (int nt = 0; nt < 4; ++nt) {
                f32x4 acc = f32x4{0.f, 0.f, 0.f, 0.f};
                #pragma unroll
                for (int kc = 0; kc < 2; ++kc) {
                    bf16x8 kf = *(const bf16x8*)&lds[kA + swz(nt * 16 + lo, kc * 32 + hi * 8)];
                    acc = __builtin_amdgcn_mfma_f32_16x16x32_bf16(qf[s][kc], kf, acc, 0, 0, 0);
                }
                sc[nt] = acc;
            }
            // causal mask (C layout: row=hi*4+r, col=nt*16+lo), only near diagonal
            if (kb + 63 > r0) {
                #pragma unroll
                for (int nt = 0; nt < 4; ++nt)
                    #pragma unroll
                    for (int r = 0; r < 4; ++r)
                        if (kb + nt * 16 + lo > r0 + hi * 4 + r) sc[nt][r] = -INFINITY;
            }
            // row max (16-lane-group butterfly)
            float pm[4];
            #pragma unroll
            for (int r = 0; r < 4; ++r) {
                float v = fmaxf(fmaxf(sc[0][r], sc[1][r]), fmaxf(sc[2][r], sc[3][r]));
                v = fmaxf(v, __shfl_xor(v, 1));
                v = fmaxf(v, __shfl_xor(v, 2));
                v = fmaxf(v, __shfl_xor(v, 4));
                v = fmaxf(v, __shfl_xor(v, 8));
                pm[r] = v;
            }
            // T13 defer-max: only rescale when new max beats old by > 8 (base-2: P <= 256, fp32-safe).
            // First live tile always triggers (mrow=-inf); fully-masked rows (pm=-inf) never do.
            bool resc = false;
            #pragma unroll
            for (int r = 0; r < 4; ++r) resc |= (pm[r] > mrow[s][r] + 8.f);
            if (__any(resc)) {
                #pragma unroll
                for (int r = 0; r < 4; ++r) {
                    const float mn = fmaxf(mrow[s][r], pm[r]);
                    const float al = __builtin_amdgcn_exp2f(mrow[s][r] - mn);
                    mrow[s][r] = mn;
                    lrow[s][r] *= al;
                    #pragma unroll
                    for (int dn = 0; dn < 4; ++dn) oacc[s][dn][r] *= al;
                }
            }
            // P = exp2(S - m), row sums
            float rs[4] = {0.f, 0.f, 0.f, 0.f};
            #pragma unroll
            for (int nt = 0; nt < 4; ++nt)
                #pragma unroll
                for (int r = 0; r < 4; ++r) {
                    float p = __builtin_amdgcn_exp2f(sc[nt][r] - mrow[s][r]);
                    sc[nt][r] = p;
                    rs[r] += p;
                }
            #pragma unroll
            for (int r = 0; r < 4; ++r) {
                float v = rs[r];
                v += __shfl_xor(v, 1);
                v += __shfl_xor(v, 2);
                v += __shfl_xor(v, 4);
                v += __shfl_xor(v, 8);
                lrow[s][r] += v;
            }
            // P -> wave-private LDS (same-wave DS ops are ordered; no barrier needed)
            #pragma unroll
            for (int nt = 0; nt < 4; ++nt)
                #pragma unroll
                for (int r = 0; r < 4; ++r)
                    lds[pbase + swz(hi * 4 + r, nt * 16 + lo)] = f2bf(sc[nt][r]);
            // PV via V^T rows (contiguous b128 reads, swizzle-uniform bank spread)
            #pragma unroll
            for (int dn = 0; dn < 4; ++dn)
                #pragma unroll
                for (int kc = 0; kc < 2; ++kc) {
                    bf16x8 pfr = *(const bf16x8*)&lds[pbase + swz(lo, kc * 32 + hi * 8)];
                    bf16x8 vfr = *(const bf16x8*)&lds[vA + swz(dn * 16 + lo, kc * 32 + hi * 8)];
                    oacc[s][dn] = __builtin_amdgcn_mfma_f32_16x16x32_bf16(pfr, vfr, oacc[s][dn], 0, 0, 0);
                }
        }

        // convert + write next tile into the OTHER buffer (readers of kA/vA unaffected)
        if (pf) {
            const int nA = ((t + 1) & 1) << 13;
            union { uint4 q; unsigned u[4]; } w;
            w.u[0] = pk2bf(kst[0][0], kst[0][1]); w.u[1] = pk2bf(kst[0][2], kst[0][3]);
            w.u[2] = pk2bf(kst[1][0], kst[1][1]); w.u[3] = pk2bf(kst[1][2], kst[1][3]);
            *(uint4*)&lds[nA + swz(kr, kcb)] = w.q;
            w.u[0] = pk2bf(kst[2][0], kst[2][1]); w.u[1] = pk2bf(kst[2][2], kst[2][3]);
            w.u[2] = pk2bf(kst[3][0], kst[3][1]); w.u[3] = pk2bf(kst[3][2], kst[3][3]);
            *(uint4*)&lds[nA + swz(kr, kcb + 8)] = w.q;
            #pragma unroll
            for (int c = 0; c < 8; ++c) {
                unsigned pv = pk2bf(vst[c >> 2][c & 3], vst[2 + (c >> 2)][c & 3]);
                *(unsigned*)&lds[nA + 4096 + swz(vcb + c, vr)] = pv;
            }
        }
        __syncthreads();   // single barrier/tile: dbuf makes write-side race-free
    }

    // epilogue: O / l
    #pragma unroll
    for (int s = 0; s < 2; ++s)
        #pragma unroll
        for (int dn = 0; dn < 4; ++dn)
            #pragma unroll
            for (int r = 0; r < 4; ++r)
                Op[(size_t)(qrow0 + s * 16 + hi * 4 + r) * D_DIM + dn * 16 + lo]
                    = oacc[s][dn][r] / lrow[s][r];
}

extern "C" void kernel_launch(void* const* d_in, const int* in_sizes, int n_in,
                              void* d_out, int out_size, void* d_ws, size_t ws_size,
                              hipStream_t stream) {
    const float* Q = (const float*)d_in[0];
    const float* K = (const float*)d_in[1];
    const float* V = (const float*)d_in[2];
    // d_in[3] (mask) unused: causality computed analytically
    float* O = (float*)d_out;
    attn_fwd<<<dim3(NQB * 32), dim3(256), 0, stream>>>(Q, K, V, O);
}

// Round 7
// 166.169 us; speedup vs baseline: 1.2460x; 1.2460x over previous
//
#include <hip/hip_runtime.h>
#include <hip/hip_bf16.h>

#define S_LEN 2048
#define D_DIM 64
#define KVB   64
#define QS    (0.125f * 1.44269504088896341f)   // 1/sqrt(64) * log2(e): softmax in base-2

using f32x4  = __attribute__((ext_vector_type(4))) float;
using bf16x8 = __attribute__((ext_vector_type(8))) short;   // 8 bf16

__device__ __forceinline__ unsigned short f2bf(float f) {
    return __builtin_bit_cast(unsigned short, __float2bfloat16(f));   // HW RNE cvt
}
__device__ __forceinline__ unsigned pk2bf(float lo, float hi) {
    return (unsigned)f2bf(lo) | ((unsigned)f2bf(hi) << 16);
}
// ushort-index swizzle for [r][64]-bf16 tiles: spreads row-stride-128B across 8 16B slots
__device__ __forceinline__ int swz(int r, int c) {
    return (r * 64 + c) ^ ((r & 7) << 3);
}

// DPP cross-lane (16-lane row domain == our lo-group): pure-VALU reduction network,
// replaces ds_bpermute-based __shfl_xor (~30 cy) with ~2 cy ops on the critical chain.
template<int C>
__device__ __forceinline__ float dppf(float x) {
    return __builtin_bit_cast(float,
        __builtin_amdgcn_mov_dpp(__builtin_bit_cast(int, x), C, 0xf, 0xf, true));
}
__device__ __forceinline__ float red16_max(float v) {
    v = fmaxf(v, dppf<0xB1>(v));    // quad_perm [1,0,3,2]  (xor 1)
    v = fmaxf(v, dppf<0x4E>(v));    // quad_perm [2,3,0,1]  (xor 2)
    v = fmaxf(v, dppf<0x141>(v));   // row_half_mirror      (other quad of 8-group)
    v = fmaxf(v, dppf<0x140>(v));   // row_mirror           (other 8-group of row16)
    return v;
}
__device__ __forceinline__ float red16_sum(float v) {
    v += dppf<0xB1>(v);
    v += dppf<0x4E>(v);
    v += dppf<0x141>(v);
    v += dppf<0x140>(v);
    return v;
}

// LDS map (ushort units): buf0 K@0 V^T@4096 | buf1 K@8192 V^T@12288 | P@16384 (1024/wave)
// 40 KB -> 4 blocks/CU by LDS; VGPR(124) caps 16 waves/CU anyway, so 4x4 waves IS the ceiling.
__global__ __launch_bounds__(256, 4)
void attn_fwd(const float* __restrict__ Qg, const float* __restrict__ Kg,
              const float* __restrict__ Vg, float* __restrict__ Og) {
    __shared__ __align__(16) unsigned short lds[20480];

    // wg = r*256 + s*8 + x  (x: XCD via round-robin dispatch, s: CU slot, r: residency round)
    // bh = x*4+r  -> each XCD sees 4 heads (~4MB L2 working set);  q = s or 31-s so the 4
    // co-resident blocks on every CU sum to 66 tile-iterations (fixes round-2's same-q tail).
    const int wg = blockIdx.x;
    const int x  = wg & 7;
    const int s  = (wg >> 3) & 31;
    const int r  = wg >> 8;
    const int bh = x * 4 + r;
    const int q  = (r & 1) ? (31 - s) : s;

    const int tid  = threadIdx.x;
    const int wid  = tid >> 6;
    const int lane = tid & 63;
    const int lo   = lane & 15;
    const int hi   = lane >> 4;

    const size_t boff = (size_t)bh * (S_LEN * D_DIM);
    const float* Qp = Qg + boff;
    const float* Kp = Kg + boff;
    const float* Vp = Vg + boff;
    float*       Op = Og + boff;

    const int qrow0 = q * 64 + wid * 16;   // wave owns one 16-row strip; active on ALL tiles

    // ---- Q fragment in registers, pre-scaled (consistent scale -> softmax-invariant)
    bf16x8 qf[2];
    #pragma unroll
    for (int kc = 0; kc < 2; ++kc) {
        const float* src = Qp + (size_t)(qrow0 + lo) * D_DIM + kc * 32 + hi * 8;
        f32x4 a = *(const f32x4*)src;
        f32x4 b = *(const f32x4*)(src + 4);
        union { bf16x8 v; unsigned u[4]; } fr;
        fr.u[0] = pk2bf(a[0] * QS, a[1] * QS);
        fr.u[1] = pk2bf(a[2] * QS, a[3] * QS);
        fr.u[2] = pk2bf(b[0] * QS, b[1] * QS);
        fr.u[3] = pk2bf(b[2] * QS, b[3] * QS);
        qf[kc] = fr.v;
    }

    float mrow[4], lrow[4];
    f32x4 oacc[4];
    #pragma unroll
    for (int rr = 0; rr < 4; ++rr) { mrow[rr] = -INFINITY; lrow[rr] = 0.f; }
    #pragma unroll
    for (int dn = 0; dn < 4; ++dn) oacc[dn] = f32x4{0.f, 0.f, 0.f, 0.f};

    // staging geometry: K: thread = 1 row x 16 cols; V: 2 adjacent rows x 8 cols (-> b32 V^T writes)
    const int kr    = tid >> 2;
    const int kcb   = (tid & 3) << 4;
    const int vr    = (tid & 31) << 1;
    const int vcb   = (tid >> 5) << 3;
    const int pbase = 16384 + (wid << 10);

    const int T = q + 1;
    f32x4 kst[4], vst[4];

    // prologue: load + stage tile 0 into buffer 0
    {
        const float* ks = Kp + (size_t)kr * D_DIM + kcb;
        kst[0] = *(const f32x4*)ks;       kst[1] = *(const f32x4*)(ks + 4);
        kst[2] = *(const f32x4*)(ks + 8); kst[3] = *(const f32x4*)(ks + 12);
        const float* vs = Vp + (size_t)vr * D_DIM + vcb;
        vst[0] = *(const f32x4*)vs;           vst[1] = *(const f32x4*)(vs + 4);
        vst[2] = *(const f32x4*)(vs + D_DIM); vst[3] = *(const f32x4*)(vs + D_DIM + 4);
        union { uint4 w4; unsigned u[4]; } w;
        w.u[0] = pk2bf(kst[0][0], kst[0][1]); w.u[1] = pk2bf(kst[0][2], kst[0][3]);
        w.u[2] = pk2bf(kst[1][0], kst[1][1]); w.u[3] = pk2bf(kst[1][2], kst[1][3]);
        *(uint4*)&lds[swz(kr, kcb)] = w.w4;
        w.u[0] = pk2bf(kst[2][0], kst[2][1]); w.u[1] = pk2bf(kst[2][2], kst[2][3]);
        w.u[2] = pk2bf(kst[3][0], kst[3][1]); w.u[3] = pk2bf(kst[3][2], kst[3][3]);
        *(uint4*)&lds[swz(kr, kcb + 8)] = w.w4;
        #pragma unroll
        for (int c = 0; c < 8; ++c) {
            unsigned pv = pk2bf(vst[c >> 2][c & 3], vst[2 + (c >> 2)][c & 3]);
            *(unsigned*)&lds[4096 + swz(vcb + c, vr)] = pv;
        }
    }
    __syncthreads();

    for (int t = 0; t < T; ++t) {
        const int kA = (t & 1) << 13;
        const int vA = kA + 4096;
        const bool pf = (t + 1 < T);

        // T14: issue next tile's global loads BEFORE compute (latency hides under MFMA/softmax)
        if (pf) {
            const int nb = (t + 1) * KVB;
            const float* ks = Kp + (size_t)(nb + kr) * D_DIM + kcb;
            kst[0] = *(const f32x4*)ks;       kst[1] = *(const f32x4*)(ks + 4);
            kst[2] = *(const f32x4*)(ks + 8); kst[3] = *(const f32x4*)(ks + 12);
            const float* vs = Vp + (size_t)(nb + vr) * D_DIM + vcb;
            vst[0] = *(const f32x4*)vs;           vst[1] = *(const f32x4*)(vs + 4);
            vst[2] = *(const f32x4*)(vs + D_DIM); vst[3] = *(const f32x4*)(vs + D_DIM + 4);
        }

        // ---- QK^T (16x64), 4 n-tiles x 2 k-chunks  [T5: favor MFMA-issuing waves]
        f32x4 sc[4];
        __builtin_amdgcn_s_setprio(1);
        #pragma unroll
        for (int nt = 0; nt < 4; ++nt) {
            f32x4 acc = f32x4{0.f, 0.f, 0.f, 0.f};
            #pragma unroll
            for (int kc = 0; kc < 2; ++kc) {
                bf16x8 kf = *(const bf16x8*)&lds[kA + swz(nt * 16 + lo, kc * 32 + hi * 8)];
                acc = __builtin_amdgcn_mfma_f32_16x16x32_bf16(qf[kc], kf, acc, 0, 0, 0);
            }
            sc[nt] = acc;
        }
        __builtin_amdgcn_s_setprio(0);
        // causal mask: only the diagonal tile (t == q) has masked entries
        if (t == q) {
            const int kb = t * KVB;
            #pragma unroll
            for (int nt = 0; nt < 4; ++nt)
                #pragma unroll
                for (int rr = 0; rr < 4; ++rr)
                    if (kb + nt * 16 + lo > qrow0 + hi * 4 + rr) sc[nt][rr] = -INFINITY;
        }
        // row max (pure-VALU DPP reduce within 16-lane group)
        float pm[4];
        #pragma unroll
        for (int rr = 0; rr < 4; ++rr)
            pm[rr] = red16_max(fmaxf(fmaxf(sc[0][rr], sc[1][rr]), fmaxf(sc[2][rr], sc[3][rr])));

        // T13 defer-max: rescale only when max grows by > 8 (base-2: P <= 256, fp32-safe).
        // First tile always triggers (mrow=-inf); diagonal rows always have >=1 live col.
        bool resc = false;
        #pragma unroll
        for (int rr = 0; rr < 4; ++rr) resc |= (pm[rr] > mrow[rr] + 8.f);
        if (__any(resc)) {
            #pragma unroll
            for (int rr = 0; rr < 4; ++rr) {
                const float mn = fmaxf(mrow[rr], pm[rr]);
                const float al = __builtin_amdgcn_exp2f(mrow[rr] - mn);
                mrow[rr] = mn;
                lrow[rr] *= al;
                #pragma unroll
                for (int dn = 0; dn < 4; ++dn) oacc[dn][rr] *= al;
            }
        }
        // P = exp2(S - m): fuse row-sum accumulation AND the P-LDS write into one loop so
        // ds_writes issue interleaved with the VALU exp chain (overlap LDS pipe w/ VALU).
        float rs[4] = {0.f, 0.f, 0.f, 0.f};
        #pragma unroll
        for (int nt = 0; nt < 4; ++nt)
            #pragma unroll
            for (int rr = 0; rr < 4; ++rr) {
                float p = __builtin_amdgcn_exp2f(sc[nt][rr] - mrow[rr]);
                rs[rr] += p;
                lds[pbase + swz(hi * 4 + rr, nt * 16 + lo)] = f2bf(p);
            }
        #pragma unroll
        for (int rr = 0; rr < 4; ++rr) lrow[rr] += red16_sum(rs[rr]);

        // PV via V^T rows (contiguous b128 reads; same-wave DS ordering makes P safe w/o barrier)
        __builtin_amdgcn_s_setprio(1);
        #pragma unroll
        for (int dn = 0; dn < 4; ++dn)
            #pragma unroll
            for (int kc = 0; kc < 2; ++kc) {
                bf16x8 pfr = *(const bf16x8*)&lds[pbase + swz(lo, kc * 32 + hi * 8)];
                bf16x8 vfr = *(const bf16x8*)&lds[vA + swz(dn * 16 + lo, kc * 32 + hi * 8)];
                oacc[dn] = __builtin_amdgcn_mfma_f32_16x16x32_bf16(pfr, vfr, oacc[dn], 0, 0, 0);
            }
        __builtin_amdgcn_s_setprio(0);

        // convert + write next tile into the OTHER buffer (readers of kA/vA unaffected)
        if (pf) {
            const int nA = ((t + 1) & 1) << 13;
            union { uint4 w4; unsigned u[4]; } w;
            w.u[0] = pk2bf(kst[0][0], kst[0][1]); w.u[1] = pk2bf(kst[0][2], kst[0][3]);
            w.u[2] = pk2bf(kst[1][0], kst[1][1]); w.u[3] = pk2bf(kst[1][2], kst[1][3]);
            *(uint4*)&lds[nA + swz(kr, kcb)] = w.w4;
            w.u[0] = pk2bf(kst[2][0], kst[2][1]); w.u[1] = pk2bf(kst[2][2], kst[2][3]);
            w.u[2] = pk2bf(kst[3][0], kst[3][1]); w.u[3] = pk2bf(kst[3][2], kst[3][3]);
            *(uint4*)&lds[nA + swz(kr, kcb + 8)] = w.w4;
            #pragma unroll
            for (int c = 0; c < 8; ++c) {
                unsigned pv = pk2bf(vst[c >> 2][c & 3], vst[2 + (c >> 2)][c & 3]);
                *(unsigned*)&lds[nA + 4096 + swz(vcb + c, vr)] = pv;
            }
        }
        __syncthreads();   // single barrier/tile: dbuf makes write-side race-free
    }

    // epilogue: O * (1/l)  -- 4 rcp + 16 mul instead of 16 full-precision divides
    #pragma unroll
    for (int rr = 0; rr < 4; ++rr) {
        const float inv = 1.0f / lrow[rr];
        #pragma unroll
        for (int dn = 0; dn < 4; ++dn)
            Op[(size_t)(qrow0 + hi * 4 + rr) * D_DIM + dn * 16 + lo] = oacc[dn][rr] * inv;
    }
}

extern "C" void kernel_launch(void* const* d_in, const int* in_sizes, int n_in,
                              void* d_out, int out_size, void* d_ws, size_t ws_size,
                              hipStream_t stream) {
    const float* Q = (const float*)d_in[0];
    const float* K = (const float*)d_in[1];
    const float* V = (const float*)d_in[2];
    // d_in[3] (mask) unused: causality computed analytically
    float* O = (float*)d_out;
    attn_fwd<<<dim3(32 * 32), dim3(256), 0, stream>>>(Q, K, V, O);
}

// Round 9
// 151.035 us; speedup vs baseline: 1.3709x; 1.1002x over previous
//
#include <hip/hip_runtime.h>
#include <hip/hip_bf16.h>

#define S_LEN 2048
#define D_DIM 64
#define KVB   64
#define QS    (0.125f * 1.44269504088896341f)   // 1/sqrt(64) * log2(e): softmax in base-2

using f32x4  = __attribute__((ext_vector_type(4))) float;
using bf16x8 = __attribute__((ext_vector_type(8))) short;   // 8 bf16

__device__ __forceinline__ unsigned short f2bf(float f) {
    return __builtin_bit_cast(unsigned short, __float2bfloat16(f));   // HW RNE cvt
}
__device__ __forceinline__ unsigned pk2bf(float lo, float hi) {
    return (unsigned)f2bf(lo) | ((unsigned)f2bf(hi) << 16);
}
// ushort-index swizzle for [r][64]-bf16 tiles; XORs byte-bits 4-6 -> moves whole 16B groups
__device__ __forceinline__ int swz(int r, int c) {
    return (r * 64 + c) ^ ((r & 7) << 3);
}

// DPP 16-lane reductions (pure VALU, ~2cy/step vs ~30cy ds_bpermute)
template<int C>
__device__ __forceinline__ float dppf(float x) {
    return __builtin_bit_cast(float,
        __builtin_amdgcn_mov_dpp(__builtin_bit_cast(int, x), C, 0xf, 0xf, true));
}
__device__ __forceinline__ float red16_max(float v) {
    v = fmaxf(v, dppf<0xB1>(v));
    v = fmaxf(v, dppf<0x4E>(v));
    v = fmaxf(v, dppf<0x141>(v));
    v = fmaxf(v, dppf<0x140>(v));
    return v;
}
__device__ __forceinline__ float red16_sum(float v) {
    v += dppf<0xB1>(v);
    v += dppf<0x4E>(v);
    v += dppf<0x141>(v);
    v += dppf<0x140>(v);
    return v;
}

// async global->LDS, 16B/lane. LDS dest = wave-uniform base + lane*16 (m104); global src
// is per-lane. AS-qualified pointers via C-style casts (clang addrspacecast — no aperture
// integer tricks).
typedef const __attribute__((address_space(1))) unsigned short* gas_p;
typedef __attribute__((address_space(3))) unsigned short*       las_p;
__device__ __forceinline__ void stage16(const unsigned short* g, unsigned short* l) {
    __builtin_amdgcn_global_load_lds((gas_p)g, (las_p)l, 16, 0, 0);
}

// ---- prep: K -> bf16, pre-swizzled tile order in ws (linear gll lands swizzled; m173)
__global__ __launch_bounds__(256)
void prep_k(const float* __restrict__ Kg, unsigned short* __restrict__ wsK) {
    const int base = (blockIdx.x * 256 + threadIdx.x) * 8;   // float idx
    const int bh   = base >> 17;
    const int rem  = base & 131071;
    const int r    = rem >> 6;
    const int c0   = rem & 63;
    f32x4 a = *(const f32x4*)(Kg + base);
    f32x4 b = *(const f32x4*)(Kg + base + 4);
    union { uint4 w4; unsigned u[4]; } w;
    w.u[0] = pk2bf(a[0], a[1]); w.u[1] = pk2bf(a[2], a[3]);
    w.u[2] = pk2bf(b[0], b[1]); w.u[3] = pk2bf(b[2], b[3]);
    *(uint4*)&wsK[bh * 131072 + (r >> 6) * 4096 + swz(r & 63, c0)] = w.w4;
}

// ---- prep: V -> V^T bf16, pre-swizzled (transpose via padded LDS, coalesced both sides)
__global__ __launch_bounds__(256)
void prep_v(const float* __restrict__ Vg, unsigned short* __restrict__ wsV) {
    __shared__ float ldsF[64 * 68];
    const int bh  = blockIdx.x >> 5;
    const int t   = blockIdx.x & 31;
    const int tid = threadIdx.x;
    const int kvr = tid >> 2;
    const int c0  = (tid & 3) << 4;
    const float* src = Vg + (size_t)bh * 131072 + (size_t)(t * 64 + kvr) * 64 + c0;
    #pragma unroll
    for (int j = 0; j < 4; ++j)
        *(f32x4*)&ldsF[kvr * 68 + c0 + j * 4] = *(const f32x4*)(src + j * 4);
    __syncthreads();
    #pragma unroll
    for (int i = 0; i < 2; ++i) {
        const int d   = tid & 63;
        const int kv0 = ((tid >> 6) << 3) + (i << 5);
        float p[8];
        #pragma unroll
        for (int j = 0; j < 8; ++j) p[j] = ldsF[(kv0 + j) * 68 + d];
        union { uint4 w4; unsigned u[4]; } w;
        w.u[0] = pk2bf(p[0], p[1]); w.u[1] = pk2bf(p[2], p[3]);
        w.u[2] = pk2bf(p[4], p[5]); w.u[3] = pk2bf(p[6], p[7]);
        *(uint4*)&wsV[bh * 131072 + t * 4096 + swz(d, kv0)] = w.w4;
    }
}

// LDS map (ushort): buf0 K@0 V^T@4096 | buf1 K@8192 V^T@12288 | P@16384 (1024/wave)
__global__ __launch_bounds__(256, 4)
void attn_fast(const float* __restrict__ Qg, const unsigned short* __restrict__ wsK,
               const unsigned short* __restrict__ wsV, float* __restrict__ Og) {
    __shared__ __align__(16) unsigned short lds[20480];

    // wg = r*256 + s*8 + x : bh = x*4+r (XCD L2 locality), q = s or 31-s (per-CU balance)
    const int wg = blockIdx.x;
    const int x  = wg & 7;
    const int s  = (wg >> 3) & 31;
    const int r  = wg >> 8;
    const int bh = x * 4 + r;
    const int q  = (r & 1) ? (31 - s) : s;

    const int tid  = threadIdx.x;
    const int wid  = tid >> 6;
    const int lane = tid & 63;
    const int lo   = lane & 15;
    const int hi   = lane >> 4;

    const float* Qp = Qg + (size_t)bh * (S_LEN * D_DIM);
    float*       Op = Og + (size_t)bh * (S_LEN * D_DIM);
    const unsigned short* kws = wsK + (size_t)bh * 131072;
    const unsigned short* vws = wsV + (size_t)bh * 131072;

    const int qrow0 = q * 64 + wid * 16;

    bf16x8 qf[2];
    #pragma unroll
    for (int kc = 0; kc < 2; ++kc) {
        const float* src = Qp + (size_t)(qrow0 + lo) * D_DIM + kc * 32 + hi * 8;
        f32x4 a = *(const f32x4*)src;
        f32x4 b = *(const f32x4*)(src + 4);
        union { bf16x8 v; unsigned u[4]; } fr;
        fr.u[0] = pk2bf(a[0] * QS, a[1] * QS);
        fr.u[1] = pk2bf(a[2] * QS, a[3] * QS);
        fr.u[2] = pk2bf(b[0] * QS, b[1] * QS);
        fr.u[3] = pk2bf(b[2] * QS, b[3] * QS);
        qf[kc] = fr.v;
    }

    float mrow[4], lrow[4];
    f32x4 oacc[4];
    #pragma unroll
    for (int rr = 0; rr < 4; ++rr) { mrow[rr] = -INFINITY; lrow[rr] = 0.f; }
    #pragma unroll
    for (int dn = 0; dn < 4; ++dn) oacc[dn] = f32x4{0.f, 0.f, 0.f, 0.f};

    const int pbase = 16384 + (wid << 10);
    const int T = q + 1;

    // prologue: async-stage tile 0 into buf0 (4 x gll16 per wave, no VALU converts)
    #pragma unroll
    for (int j = 0; j < 2; ++j) {
        const int so = (wid * 2 + j) * 512;
        stage16(kws + so + lane * 8, &lds[so]);
        stage16(vws + so + lane * 8, &lds[4096 + so]);
    }
    __syncthreads();   // compiler emits vmcnt(0) before s_barrier -> staging complete

    for (int t = 0; t < T; ++t) {
        const int kA = (t & 1) << 13;
        const int vA = kA + 4096;
        const bool pf = (t + 1 < T);

        // T14/T3: issue next tile's gll into the other buffer; completes during compute
        if (pf) {
            const int nA = ((t + 1) & 1) << 13;
            const int tb = (t + 1) * 4096;
            #pragma unroll
            for (int j = 0; j < 2; ++j) {
                const int so = (wid * 2 + j) * 512;
                stage16(kws + tb + so + lane * 8, &lds[nA + so]);
                stage16(vws + tb + so + lane * 8, &lds[nA + 4096 + so]);
            }
        }

        // ---- QK^T (16x64)
        f32x4 sc[4];
        __builtin_amdgcn_s_setprio(1);
        #pragma unroll
        for (int nt = 0; nt < 4; ++nt) {
            f32x4 acc = f32x4{0.f, 0.f, 0.f, 0.f};
            #pragma unroll
            for (int kc = 0; kc < 2; ++kc) {
                bf16x8 kf = *(const bf16x8*)&lds[kA + swz(nt * 16 + lo, kc * 32 + hi * 8)];
                acc = __builtin_amdgcn_mfma_f32_16x16x32_bf16(qf[kc], kf, acc, 0, 0, 0);
            }
            sc[nt] = acc;
        }
        __builtin_amdgcn_s_setprio(0);
        // causal mask: only diagonal tile
        if (t == q) {
            const int kb = t * KVB;
            #pragma unroll
            for (int nt = 0; nt < 4; ++nt)
                #pragma unroll
                for (int rr = 0; rr < 4; ++rr)
                    if (kb + nt * 16 + lo > qrow0 + hi * 4 + rr) sc[nt][rr] = -INFINITY;
        }
        // row max
        float pm[4];
        #pragma unroll
        for (int rr = 0; rr < 4; ++rr)
            pm[rr] = red16_max(fmaxf(fmaxf(sc[0][rr], sc[1][rr]), fmaxf(sc[2][rr], sc[3][rr])));

        // T13 defer-max (base-2: P <= 256, fp32-safe)
        bool resc = false;
        #pragma unroll
        for (int rr = 0; rr < 4; ++rr) resc |= (pm[rr] > mrow[rr] + 8.f);
        if (__any(resc)) {
            #pragma unroll
            for (int rr = 0; rr < 4; ++rr) {
                const float mn = fmaxf(mrow[rr], pm[rr]);
                const float al = __builtin_amdgcn_exp2f(mrow[rr] - mn);
                mrow[rr] = mn;
                lrow[rr] *= al;
                #pragma unroll
                for (int dn = 0; dn < 4; ++dn) oacc[dn][rr] *= al;
            }
        }
        // P = exp2(S - m): fused sum + LDS write (ds interleaves with VALU exp chain)
        float rs[4] = {0.f, 0.f, 0.f, 0.f};
        #pragma unroll
        for (int nt = 0; nt < 4; ++nt)
            #pragma unroll
            for (int rr = 0; rr < 4; ++rr) {
                float p = __builtin_amdgcn_exp2f(sc[nt][rr] - mrow[rr]);
                rs[rr] += p;
                lds[pbase + swz(hi * 4 + rr, nt * 16 + lo)] = f2bf(p);
            }
        #pragma unroll
        for (int rr = 0; rr < 4; ++rr) lrow[rr] += red16_sum(rs[rr]);

        // PV via V^T rows
        __builtin_amdgcn_s_setprio(1);
        #pragma unroll
        for (int dn = 0; dn < 4; ++dn)
            #pragma unroll
            for (int kc = 0; kc < 2; ++kc) {
                bf16x8 pfr = *(const bf16x8*)&lds[pbase + swz(lo, kc * 32 + hi * 8)];
                bf16x8 vfr = *(const bf16x8*)&lds[vA + swz(dn * 16 + lo, kc * 32 + hi * 8)];
                oacc[dn] = __builtin_amdgcn_mfma_f32_16x16x32_bf16(pfr, vfr, oacc[dn], 0, 0, 0);
            }
        __builtin_amdgcn_s_setprio(0);

        __syncthreads();   // vmcnt(0)+barrier: prefetch landed, all waves done reading
    }

    #pragma unroll
    for (int rr = 0; rr < 4; ++rr) {
        const float inv = 1.0f / lrow[rr];
        #pragma unroll
        for (int dn = 0; dn < 4; ++dn)
            Op[(size_t)(qrow0 + hi * 4 + rr) * D_DIM + dn * 16 + lo] = oacc[dn][rr] * inv;
    }
}

// ---- fallback (round-6 proven kernel): used only if ws_size < 16 MB
__global__ __launch_bounds__(256, 4)
void attn_fb(const float* __restrict__ Qg, const float* __restrict__ Kg,
             const float* __restrict__ Vg, float* __restrict__ Og) {
    __shared__ __align__(16) unsigned short lds[20480];
    const int wg = blockIdx.x;
    const int x  = wg & 7;
    const int s  = (wg >> 3) & 31;
    const int r  = wg >> 8;
    const int bh = x * 4 + r;
    const int q  = (r & 1) ? (31 - s) : s;
    const int tid  = threadIdx.x;
    const int wid  = tid >> 6;
    const int lane = tid & 63;
    const int lo   = lane & 15;
    const int hi   = lane >> 4;
    const size_t boff = (size_t)bh * (S_LEN * D_DIM);
    const float* Qp = Qg + boff;
    const float* Kp = Kg + boff;
    const float* Vp = Vg + boff;
    float*       Op = Og + boff;
    const int qrow0 = q * 64 + wid * 16;
    bf16x8 qf[2];
    #pragma unroll
    for (int kc = 0; kc < 2; ++kc) {
        const float* src = Qp + (size_t)(qrow0 + lo) * D_DIM + kc * 32 + hi * 8;
        f32x4 a = *(const f32x4*)src;
        f32x4 b = *(const f32x4*)(src + 4);
        union { bf16x8 v; unsigned u[4]; } fr;
        fr.u[0] = pk2bf(a[0] * QS, a[1] * QS);
        fr.u[1] = pk2bf(a[2] * QS, a[3] * QS);
        fr.u[2] = pk2bf(b[0] * QS, b[1] * QS);
        fr.u[3] = pk2bf(b[2] * QS, b[3] * QS);
        qf[kc] = fr.v;
    }
    float mrow[4], lrow[4];
    f32x4 oacc[4];
    #pragma unroll
    for (int rr = 0; rr < 4; ++rr) { mrow[rr] = -INFINITY; lrow[rr] = 0.f; }
    #pragma unroll
    for (int dn = 0; dn < 4; ++dn) oacc[dn] = f32x4{0.f, 0.f, 0.f, 0.f};
    const int kr    = tid >> 2;
    const int kcb   = (tid & 3) << 4;
    const int vr    = (tid & 31) << 1;
    const int vcb   = (tid >> 5) << 3;
    const int pbase = 16384 + (wid << 10);
    const int T = q + 1;
    f32x4 kst[4], vst[4];
    {
        const float* ks = Kp + (size_t)kr * D_DIM + kcb;
        kst[0] = *(const f32x4*)ks;       kst[1] = *(const f32x4*)(ks + 4);
        kst[2] = *(const f32x4*)(ks + 8); kst[3] = *(const f32x4*)(ks + 12);
        const float* vs = Vp + (size_t)vr * D_DIM + vcb;
        vst[0] = *(const f32x4*)vs;           vst[1] = *(const f32x4*)(vs + 4);
        vst[2] = *(const f32x4*)(vs + D_DIM); vst[3] = *(const f32x4*)(vs + D_DIM + 4);
        union { uint4 w4; unsigned u[4]; } w;
        w.u[0] = pk2bf(kst[0][0], kst[0][1]); w.u[1] = pk2bf(kst[0][2], kst[0][3]);
        w.u[2] = pk2bf(kst[1][0], kst[1][1]); w.u[3] = pk2bf(kst[1][2], kst[1][3]);
        *(uint4*)&lds[swz(kr, kcb)] = w.w4;
        w.u[0] = pk2bf(kst[2][0], kst[2][1]); w.u[1] = pk2bf(kst[2][2], kst[2][3]);
        w.u[2] = pk2bf(kst[3][0], kst[3][1]); w.u[3] = pk2bf(kst[3][2], kst[3][3]);
        *(uint4*)&lds[swz(kr, kcb + 8)] = w.w4;
        #pragma unroll
        for (int c = 0; c < 8; ++c) {
            unsigned pv = pk2bf(vst[c >> 2][c & 3], vst[2 + (c >> 2)][c & 3]);
            *(unsigned*)&lds[4096 + swz(vcb + c, vr)] = pv;
        }
    }
    __syncthreads();
    for (int t = 0; t < T; ++t) {
        const int kA = (t & 1) << 13;
        const int vA = kA + 4096;
        const bool pf = (t + 1 < T);
        if (pf) {
            const int nb = (t + 1) * KVB;
            const float* ks = Kp + (size_t)(nb + kr) * D_DIM + kcb;
            kst[0] = *(const f32x4*)ks;       kst[1] = *(const f32x4*)(ks + 4);
            kst[2] = *(const f32x4*)(ks + 8); kst[3] = *(const f32x4*)(ks + 12);
            const float* vs = Vp + (size_t)(nb + vr) * D_DIM + vcb;
            vst[0] = *(const f32x4*)vs;           vst[1] = *(const f32x4*)(vs + 4);
            vst[2] = *(const f32x4*)(vs + D_DIM); vst[3] = *(const f32x4*)(vs + D_DIM + 4);
        }
        f32x4 sc[4];
        __builtin_amdgcn_s_setprio(1);
        #pragma unroll
        for (int nt = 0; nt < 4; ++nt) {
            f32x4 acc = f32x4{0.f, 0.f, 0.f, 0.f};
            #pragma unroll
            for (int kc = 0; kc < 2; ++kc) {
                bf16x8 kf = *(const bf16x8*)&lds[kA + swz(nt * 16 + lo, kc * 32 + hi * 8)];
                acc = __builtin_amdgcn_mfma_f32_16x16x32_bf16(qf[kc], kf, acc, 0, 0, 0);
            }
            sc[nt] = acc;
        }
        __builtin_amdgcn_s_setprio(0);
        if (t == q) {
            const int kb = t * KVB;
            #pragma unroll
            for (int nt = 0; nt < 4; ++nt)
                #pragma unroll
                for (int rr = 0; rr < 4; ++rr)
                    if (kb + nt * 16 + lo > qrow0 + hi * 4 + rr) sc[nt][rr] = -INFINITY;
        }
        float pm[4];
        #pragma unroll
        for (int rr = 0; rr < 4; ++rr)
            pm[rr] = red16_max(fmaxf(fmaxf(sc[0][rr], sc[1][rr]), fmaxf(sc[2][rr], sc[3][rr])));
        bool resc = false;
        #pragma unroll
        for (int rr = 0; rr < 4; ++rr) resc |= (pm[rr] > mrow[rr] + 8.f);
        if (__any(resc)) {
            #pragma unroll
            for (int rr = 0; rr < 4; ++rr) {
                const float mn = fmaxf(mrow[rr], pm[rr]);
                const float al = __builtin_amdgcn_exp2f(mrow[rr] - mn);
                mrow[rr] = mn;
                lrow[rr] *= al;
                #pragma unroll
                for (int dn = 0; dn < 4; ++dn) oacc[dn][rr] *= al;
            }
        }
        float rs[4] = {0.f, 0.f, 0.f, 0.f};
        #pragma unroll
        for (int nt = 0; nt < 4; ++nt)
            #pragma unroll
            for (int rr = 0; rr < 4; ++rr) {
                float p = __builtin_amdgcn_exp2f(sc[nt][rr] - mrow[rr]);
                rs[rr] += p;
                lds[pbase + swz(hi * 4 + rr, nt * 16 + lo)] = f2bf(p);
            }
        #pragma unroll
        for (int rr = 0; rr < 4; ++rr) lrow[rr] += red16_sum(rs[rr]);
        __builtin_amdgcn_s_setprio(1);
        #pragma unroll
        for (int dn = 0; dn < 4; ++dn)
            #pragma unroll
            for (int kc = 0; kc < 2; ++kc) {
                bf16x8 pfr = *(const bf16x8*)&lds[pbase + swz(lo, kc * 32 + hi * 8)];
                bf16x8 vfr = *(const bf16x8*)&lds[vA + swz(dn * 16 + lo, kc * 32 + hi * 8)];
                oacc[dn] = __builtin_amdgcn_mfma_f32_16x16x32_bf16(pfr, vfr, oacc[dn], 0, 0, 0);
            }
        __builtin_amdgcn_s_setprio(0);
        if (pf) {
            const int nA = ((t + 1) & 1) << 13;
            union { uint4 w4; unsigned u[4]; } w;
            w.u[0] = pk2bf(kst[0][0], kst[0][1]); w.u[1] = pk2bf(kst[0][2], kst[0][3]);
            w.u[2] = pk2bf(kst[1][0], kst[1][1]); w.u[3] = pk2bf(kst[1][2], kst[1][3]);
            *(uint4*)&lds[nA + swz(kr, kcb)] = w.w4;
            w.u[0] = pk2bf(kst[2][0], kst[2][1]); w.u[1] = pk2bf(kst[2][2], kst[2][3]);
            w.u[2] = pk2bf(kst[3][0], kst[3][1]); w.u[3] = pk2bf(kst[3][2], kst[3][3]);
            *(uint4*)&lds[nA + swz(kr, kcb + 8)] = w.w4;
            #pragma unroll
            for (int c = 0; c < 8; ++c) {
                unsigned pv = pk2bf(vst[c >> 2][c & 3], vst[2 + (c >> 2)][c & 3]);
                *(unsigned*)&lds[nA + 4096 + swz(vcb + c, vr)] = pv;
            }
        }
        __syncthreads();
    }
    #pragma unroll
    for (int rr = 0; rr < 4; ++rr) {
        const float inv = 1.0f / lrow[rr];
        #pragma unroll
        for (int dn = 0; dn < 4; ++dn)
            Op[(size_t)(qrow0 + hi * 4 + rr) * D_DIM + dn * 16 + lo] = oacc[dn][rr] * inv;
    }
}

extern "C" void kernel_launch(void* const* d_in, const int* in_sizes, int n_in,
                              void* d_out, int out_size, void* d_ws, size_t ws_size,
                              hipStream_t stream) {
    const float* Q = (const float*)d_in[0];
    const float* K = (const float*)d_in[1];
    const float* V = (const float*)d_in[2];
    float* O = (float*)d_out;
    const size_t wsNeed = (size_t)32 * 131072 * 2 * sizeof(unsigned short);   // 16 MB
    if (ws_size >= wsNeed) {
        unsigned short* wsK = (unsigned short*)d_ws;
        unsigned short* wsV = wsK + (size_t)32 * 131072;
        prep_k<<<dim3(2048), dim3(256), 0, stream>>>(K, wsK);
        prep_v<<<dim3(1024), dim3(256), 0, stream>>>(V, wsV);
        attn_fast<<<dim3(1024), dim3(256), 0, stream>>>(Q, wsK, wsV, O);
    } else {
        attn_fb<<<dim3(1024), dim3(256), 0, stream>>>(Q, K, V, O);
    }
}

// Round 11
// 149.203 us; speedup vs baseline: 1.3877x; 1.0123x over previous
//
#include <hip/hip_runtime.h>
#include <hip/hip_bf16.h>

#define S_LEN 2048
#define D_DIM 64
#define KVB   64
#define QS    (0.125f * 1.44269504088896341f)   // 1/sqrt(64) * log2(e): softmax in base-2

using f32x4  = __attribute__((ext_vector_type(4))) float;
using bf16x8 = __attribute__((ext_vector_type(8))) short;   // 8 bf16

__device__ __forceinline__ unsigned short f2bf(float f) {
    return __builtin_bit_cast(unsigned short, __float2bfloat16(f));   // HW RNE cvt
}
__device__ __forceinline__ unsigned pk2bf(float lo, float hi) {
    return (unsigned)f2bf(lo) | ((unsigned)f2bf(hi) << 16);
}
// ushort-index swizzle for [r][64]-bf16 tiles; XORs 16B-group bits by row
__device__ __forceinline__ int swz(int r, int c) {
    return (r * 64 + c) ^ ((r & 7) << 3);
}

// DPP 16-lane reductions (pure VALU)
template<int C>
__device__ __forceinline__ float dppf(float x) {
    return __builtin_bit_cast(float,
        __builtin_amdgcn_mov_dpp(__builtin_bit_cast(int, x), C, 0xf, 0xf, true));
}
__device__ __forceinline__ float red16_max(float v) {
    v = fmaxf(v, dppf<0xB1>(v));
    v = fmaxf(v, dppf<0x4E>(v));
    v = fmaxf(v, dppf<0x141>(v));
    v = fmaxf(v, dppf<0x140>(v));
    return v;
}
__device__ __forceinline__ float red16_sum(float v) {
    v += dppf<0xB1>(v);
    v += dppf<0x4E>(v);
    v += dppf<0x141>(v);
    v += dppf<0x140>(v);
    return v;
}

// async global->LDS, 16B/lane (dest = wave-uniform base + lane*16; src per-lane)
typedef const __attribute__((address_space(1))) unsigned short* gas_p;
typedef __attribute__((address_space(3))) unsigned short*       las_p;
__device__ __forceinline__ void stage16(const unsigned short* g, unsigned short* l) {
    __builtin_amdgcn_global_load_lds((gas_p)g, (las_p)l, 16, 0, 0);
}

// ---- prep (merged): K -> bf16 swizzled tiles; V -> V^T bf16 swizzled tiles (coalesced dump)
__global__ __launch_bounds__(256)
void prep_kv(const float* __restrict__ Kg, const float* __restrict__ Vg,
             unsigned short* __restrict__ wsK, unsigned short* __restrict__ wsV) {
    __shared__ float vf[64 * 68];                       // padded f32 V tile
    __shared__ __align__(16) unsigned short vt[4096];   // V^T swizzled bf16 image
    const int bh  = blockIdx.x >> 5;
    const int t   = blockIdx.x & 31;
    const int tid = threadIdx.x;
    const size_t gbase = (size_t)bh * 131072 + (size_t)t * 4096;   // float offset of tile
    {
        const int e  = tid * 16;
        const int r  = e >> 6;
        const int c0 = e & 63;
        const float* src = Kg + gbase + e;
        f32x4 a = *(const f32x4*)src;
        f32x4 b = *(const f32x4*)(src + 4);
        f32x4 cc = *(const f32x4*)(src + 8);
        f32x4 d = *(const f32x4*)(src + 12);
        union { uint4 w4; unsigned u[4]; } w;
        w.u[0] = pk2bf(a[0], a[1]);  w.u[1] = pk2bf(a[2], a[3]);
        w.u[2] = pk2bf(b[0], b[1]);  w.u[3] = pk2bf(b[2], b[3]);
        *(uint4*)&wsK[gbase + swz(r, c0)] = w.w4;
        w.u[0] = pk2bf(cc[0], cc[1]); w.u[1] = pk2bf(cc[2], cc[3]);
        w.u[2] = pk2bf(d[0], d[1]);   w.u[3] = pk2bf(d[2], d[3]);
        *(uint4*)&wsK[gbase + swz(r, c0 + 8)] = w.w4;
        const float* vsrc = Vg + gbase + e;
        *(f32x4*)&vf[r * 68 + c0]      = *(const f32x4*)vsrc;
        *(f32x4*)&vf[r * 68 + c0 + 4]  = *(const f32x4*)(vsrc + 4);
        *(f32x4*)&vf[r * 68 + c0 + 8]  = *(const f32x4*)(vsrc + 8);
        *(f32x4*)&vf[r * 68 + c0 + 12] = *(const f32x4*)(vsrc + 12);
    }
    __syncthreads();
    {
        const int d   = tid & 63;
        const int kv0 = (tid >> 6) << 4;
        float p[16];
        #pragma unroll
        for (int j = 0; j < 16; ++j) p[j] = vf[(kv0 + j) * 68 + d];
        union { uint4 w4; unsigned u[4]; } w;
        w.u[0] = pk2bf(p[0], p[1]);   w.u[1] = pk2bf(p[2], p[3]);
        w.u[2] = pk2bf(p[4], p[5]);   w.u[3] = pk2bf(p[6], p[7]);
        *(uint4*)&vt[swz(d, kv0)] = w.w4;
        w.u[0] = pk2bf(p[8], p[9]);   w.u[1] = pk2bf(p[10], p[11]);
        w.u[2] = pk2bf(p[12], p[13]); w.u[3] = pk2bf(p[14], p[15]);
        *(uint4*)&vt[swz(d, kv0 + 8)] = w.w4;
    }
    __syncthreads();
    {   // linear coalesced dump of the 8 KB image
        uint4* dst = (uint4*)&wsV[gbase];
        const uint4* srcv = (const uint4*)vt;
        dst[tid] = srcv[tid];
        dst[tid + 256] = srcv[tid + 256];
    }
}

// ---- split-K attention: block = (bh, q-tile, chunk); chunk0 = tiles[0,16), chunk1 = [16,q]
// LDS (ushort): buf0 K@0 V^T@4096 | buf1 K@8192 V^T@12288 | P@16384 (1024/wave)
__global__ __launch_bounds__(256, 4)
void attn_sp(const float* __restrict__ Qg, const unsigned short* __restrict__ wsK,
             const unsigned short* __restrict__ wsV, float* __restrict__ Og,
             float* __restrict__ wsP) {
    __shared__ __align__(16) unsigned short lds[20480];

    // blk -> xcd (L2 locality), heavy-chunks-first within xcd, bh interleaved
    const int blk    = blockIdx.x;
    const int xcd    = blk & 7;
    const int within = blk >> 3;          // 0..191
    const int w      = within >> 2;       // 0..47, heavy-first order
    const int bh     = xcd * 4 + (within & 3);
    int q, c;
    if (w < 32) { q = 31 - (w >> 1); c = w & 1; }
    else        { q = 47 - w;        c = 0;     }
    const int nc   = (q >= 16) ? 2 : 1;
    const int t0   = (c == 0) ? 0 : 16;
    const int tEnd = (c == 0 && q >= 16) ? 16 : (q + 1);

    const int tid  = threadIdx.x;
    const int wid  = tid >> 6;
    const int lane = tid & 63;
    const int lo   = lane & 15;
    const int hi   = lane >> 4;

    const float* Qp = Qg + (size_t)bh * (S_LEN * D_DIM);
    float*       Op = Og + (size_t)bh * (S_LEN * D_DIM);
    const unsigned short* kws = wsK + (size_t)bh * 131072;
    const unsigned short* vws = wsV + (size_t)bh * 131072;

    const int qrow0 = q * 64 + wid * 16;

    bf16x8 qf[2];
    #pragma unroll
    for (int kc = 0; kc < 2; ++kc) {
        const float* src = Qp + (size_t)(qrow0 + lo) * D_DIM + kc * 32 + hi * 8;
        f32x4 a = *(const f32x4*)src;
        f32x4 b = *(const f32x4*)(src + 4);
        union { bf16x8 v; unsigned u[4]; } fr;
        fr.u[0] = pk2bf(a[0] * QS, a[1] * QS);
        fr.u[1] = pk2bf(a[2] * QS, a[3] * QS);
        fr.u[2] = pk2bf(b[0] * QS, b[1] * QS);
        fr.u[3] = pk2bf(b[2] * QS, b[3] * QS);
        qf[kc] = fr.v;
    }

    float mrow[4], lrow[4];
    f32x4 oacc[4];
    #pragma unroll
    for (int rr = 0; rr < 4; ++rr) { mrow[rr] = -INFINITY; lrow[rr] = 0.f; }
    #pragma unroll
    for (int dn = 0; dn < 4; ++dn) oacc[dn] = f32x4{0.f, 0.f, 0.f, 0.f};

    const int pbase = 16384 + (wid << 10);

    // prologue: async-stage tile t0 into buf0 (t0 is even -> parity 0)
    {
        const int tb = t0 * 4096;
        #pragma unroll
        for (int j = 0; j < 2; ++j) {
            const int so = (wid * 2 + j) * 512;
            stage16(kws + tb + so + lane * 8, &lds[so]);
            stage16(vws + tb + so + lane * 8, &lds[4096 + so]);
        }
    }
    __syncthreads();

    for (int t = t0; t < tEnd; ++t) {
        const int kA = (t & 1) << 13;
        const int vA = kA + 4096;
        const bool pf = (t + 1 < tEnd);

        if (pf) {
            const int nA = ((t + 1) & 1) << 13;
            const int tb = (t + 1) * 4096;
            #pragma unroll
            for (int j = 0; j < 2; ++j) {
                const int so = (wid * 2 + j) * 512;
                stage16(kws + tb + so + lane * 8, &lds[nA + so]);
                stage16(vws + tb + so + lane * 8, &lds[nA + 4096 + so]);
            }
        }

        // QK^T (16x64)
        f32x4 sc[4];
        __builtin_amdgcn_s_setprio(1);
        #pragma unroll
        for (int nt = 0; nt < 4; ++nt) {
            f32x4 acc = f32x4{0.f, 0.f, 0.f, 0.f};
            #pragma unroll
            for (int kc = 0; kc < 2; ++kc) {
                bf16x8 kf = *(const bf16x8*)&lds[kA + swz(nt * 16 + lo, kc * 32 + hi * 8)];
                acc = __builtin_amdgcn_mfma_f32_16x16x32_bf16(qf[kc], kf, acc, 0, 0, 0);
            }
            sc[nt] = acc;
        }
        __builtin_amdgcn_s_setprio(0);
        if (t == q) {   // diagonal tile only
            const int kb = t * KVB;
            #pragma unroll
            for (int nt = 0; nt < 4; ++nt)
                #pragma unroll
                for (int rr = 0; rr < 4; ++rr)
                    if (kb + nt * 16 + lo > qrow0 + hi * 4 + rr) sc[nt][rr] = -INFINITY;
        }
        float pm[4];
        #pragma unroll
        for (int rr = 0; rr < 4; ++rr)
            pm[rr] = red16_max(fmaxf(fmaxf(sc[0][rr], sc[1][rr]), fmaxf(sc[2][rr], sc[3][rr])));

        bool resc = false;
        #pragma unroll
        for (int rr = 0; rr < 4; ++rr) resc |= (pm[rr] > mrow[rr] + 8.f);
        if (__any(resc)) {
            #pragma unroll
            for (int rr = 0; rr < 4; ++rr) {
                const float mn = fmaxf(mrow[rr], pm[rr]);
                const float al = __builtin_amdgcn_exp2f(mrow[rr] - mn);
                mrow[rr] = mn;
                lrow[rr] *= al;
                #pragma unroll
                for (int dn = 0; dn < 4; ++dn) oacc[dn][rr] *= al;
            }
        }
        float rs[4] = {0.f, 0.f, 0.f, 0.f};
        #pragma unroll
        for (int nt = 0; nt < 4; ++nt)
            #pragma unroll
            for (int rr = 0; rr < 4; ++rr) {
                float p = __builtin_amdgcn_exp2f(sc[nt][rr] - mrow[rr]);
                rs[rr] += p;
                lds[pbase + swz(hi * 4 + rr, nt * 16 + lo)] = f2bf(p);
            }
        #pragma unroll
        for (int rr = 0; rr < 4; ++rr) lrow[rr] += red16_sum(rs[rr]);

        __builtin_amdgcn_s_setprio(1);
        #pragma unroll
        for (int dn = 0; dn < 4; ++dn)
            #pragma unroll
            for (int kc = 0; kc < 2; ++kc) {
                bf16x8 pfr = *(const bf16x8*)&lds[pbase + swz(lo, kc * 32 + hi * 8)];
                bf16x8 vfr = *(const bf16x8*)&lds[vA + swz(dn * 16 + lo, kc * 32 + hi * 8)];
                oacc[dn] = __builtin_amdgcn_mfma_f32_16x16x32_bf16(pfr, vfr, oacc[dn], 0, 0, 0);
            }
        __builtin_amdgcn_s_setprio(0);

        __syncthreads();
    }

    if (nc == 1) {   // direct write
        #pragma unroll
        for (int rr = 0; rr < 4; ++rr) {
            const float inv = 1.0f / lrow[rr];
            #pragma unroll
            for (int dn = 0; dn < 4; ++dn)
                Op[(size_t)(qrow0 + hi * 4 + rr) * D_DIM + dn * 16 + lo] = oacc[dn][rr] * inv;
        }
    } else {         // partial slot: O[64][64] f32 + m[64] + l[64]
        float* slot = wsP + (size_t)(bh * 32 + (q - 16) * 2 + c) * 4224;
        #pragma unroll
        for (int rr = 0; rr < 4; ++rr) {
            const int row = wid * 16 + hi * 4 + rr;
            #pragma unroll
            for (int dn = 0; dn < 4; ++dn)
                slot[row * 64 + dn * 16 + lo] = oacc[dn][rr];
        }
        if (lo == 0) {
            #pragma unroll
            for (int rr = 0; rr < 4; ++rr) {
                const int row = wid * 16 + hi * 4 + rr;
                slot[4096 + row] = mrow[rr];
                slot[4160 + row] = lrow[rr];
            }
        }
    }
}

// ---- combine: merge the 2 chunks of each q>=16 tile
__global__ __launch_bounds__(256)
void combine_k(const float* __restrict__ wsP, float* __restrict__ Og) {
    const int bh  = blockIdx.x >> 4;
    const int qq  = blockIdx.x & 15;
    const int q   = 16 + qq;
    const int tid = threadIdx.x;
    const int row = tid >> 2;
    const int cg  = (tid & 3) << 4;
    const float* s0 = wsP + (size_t)(bh * 32 + qq * 2) * 4224;
    const float* s1 = s0 + 4224;
    const float m0 = s0[4096 + row], l0 = s0[4160 + row];
    const float m1 = s1[4096 + row], l1 = s1[4160 + row];
    const float M  = fmaxf(m0, m1);
    const float w0 = __builtin_amdgcn_exp2f(m0 - M);
    const float w1 = __builtin_amdgcn_exp2f(m1 - M);
    const float inv = 1.0f / (w0 * l0 + w1 * l1);
    float* dst = Og + (size_t)bh * 131072 + (size_t)(q * 64 + row) * 64 + cg;
    #pragma unroll
    for (int j = 0; j < 16; j += 4) {
        f32x4 a = *(const f32x4*)(s0 + row * 64 + cg + j);
        f32x4 b = *(const f32x4*)(s1 + row * 64 + cg + j);
        f32x4 o;
        #pragma unroll
        for (int e = 0; e < 4; ++e) o[e] = (w0 * a[e] + w1 * b[e]) * inv;
        *(f32x4*)(dst + j) = o;
    }
}

// ---- tier-2: round-9 measured kernel (no split; one block per (bh, q-tile))
__global__ __launch_bounds__(256, 4)
void attn_fast(const float* __restrict__ Qg, const unsigned short* __restrict__ wsK,
               const unsigned short* __restrict__ wsV, float* __restrict__ Og) {
    __shared__ __align__(16) unsigned short lds[20480];
    const int wg = blockIdx.x;
    const int x  = wg & 7;
    const int s  = (wg >> 3) & 31;
    const int r  = wg >> 8;
    const int bh = x * 4 + r;
    const int q  = (r & 1) ? (31 - s) : s;
    const int tid  = threadIdx.x;
    const int wid  = tid >> 6;
    const int lane = tid & 63;
    const int lo   = lane & 15;
    const int hi   = lane >> 4;
    const float* Qp = Qg + (size_t)bh * (S_LEN * D_DIM);
    float*       Op = Og + (size_t)bh * (S_LEN * D_DIM);
    const unsigned short* kws = wsK + (size_t)bh * 131072;
    const unsigned short* vws = wsV + (size_t)bh * 131072;
    const int qrow0 = q * 64 + wid * 16;
    bf16x8 qf[2];
    #pragma unroll
    for (int kc = 0; kc < 2; ++kc) {
        const float* src = Qp + (size_t)(qrow0 + lo) * D_DIM + kc * 32 + hi * 8;
        f32x4 a = *(const f32x4*)src;
        f32x4 b = *(const f32x4*)(src + 4);
        union { bf16x8 v; unsigned u[4]; } fr;
        fr.u[0] = pk2bf(a[0] * QS, a[1] * QS);
        fr.u[1] = pk2bf(a[2] * QS, a[3] * QS);
        fr.u[2] = pk2bf(b[0] * QS, b[1] * QS);
        fr.u[3] = pk2bf(b[2] * QS, b[3] * QS);
        qf[kc] = fr.v;
    }
    float mrow[4], lrow[4];
    f32x4 oacc[4];
    #pragma unroll
    for (int rr = 0; rr < 4; ++rr) { mrow[rr] = -INFINITY; lrow[rr] = 0.f; }
    #pragma unroll
    for (int dn = 0; dn < 4; ++dn) oacc[dn] = f32x4{0.f, 0.f, 0.f, 0.f};
    const int pbase = 16384 + (wid << 10);
    const int T = q + 1;
    #pragma unroll
    for (int j = 0; j < 2; ++j) {
        const int so = (wid * 2 + j) * 512;
        stage16(kws + so + lane * 8, &lds[so]);
        stage16(vws + so + lane * 8, &lds[4096 + so]);
    }
    __syncthreads();
    for (int t = 0; t < T; ++t) {
        const int kA = (t & 1) << 13;
        const int vA = kA + 4096;
        const bool pf = (t + 1 < T);
        if (pf) {
            const int nA = ((t + 1) & 1) << 13;
            const int tb = (t + 1) * 4096;
            #pragma unroll
            for (int j = 0; j < 2; ++j) {
                const int so = (wid * 2 + j) * 512;
                stage16(kws + tb + so + lane * 8, &lds[nA + so]);
                stage16(vws + tb + so + lane * 8, &lds[nA + 4096 + so]);
            }
        }
        f32x4 sc[4];
        __builtin_amdgcn_s_setprio(1);
        #pragma unroll
        for (int nt = 0; nt < 4; ++nt) {
            f32x4 acc = f32x4{0.f, 0.f, 0.f, 0.f};
            #pragma unroll
            for (int kc = 0; kc < 2; ++kc) {
                bf16x8 kf = *(const bf16x8*)&lds[kA + swz(nt * 16 + lo, kc * 32 + hi * 8)];
                acc = __builtin_amdgcn_mfma_f32_16x16x32_bf16(qf[kc], kf, acc, 0, 0, 0);
            }
            sc[nt] = acc;
        }
        __builtin_amdgcn_s_setprio(0);
        if (t == q) {
            const int kb = t * KVB;
            #pragma unroll
            for (int nt = 0; nt < 4; ++nt)
                #pragma unroll
                for (int rr = 0; rr < 4; ++rr)
                    if (kb + nt * 16 + lo > qrow0 + hi * 4 + rr) sc[nt][rr] = -INFINITY;
        }
        float pm[4];
        #pragma unroll
        for (int rr = 0; rr < 4; ++rr)
            pm[rr] = red16_max(fmaxf(fmaxf(sc[0][rr], sc[1][rr]), fmaxf(sc[2][rr], sc[3][rr])));
        bool resc = false;
        #pragma unroll
        for (int rr = 0; rr < 4; ++rr) resc |= (pm[rr] > mrow[rr] + 8.f);
        if (__any(resc)) {
            #pragma unroll
            for (int rr = 0; rr < 4; ++rr) {
                const float mn = fmaxf(mrow[rr], pm[rr]);
                const float al = __builtin_amdgcn_exp2f(mrow[rr] - mn);
                mrow[rr] = mn;
                lrow[rr] *= al;
                #pragma unroll
                for (int dn = 0; dn < 4; ++dn) oacc[dn][rr] *= al;
            }
        }
        float rs[4] = {0.f, 0.f, 0.f, 0.f};
        #pragma unroll
        for (int nt = 0; nt < 4; ++nt)
            #pragma unroll
            for (int rr = 0; rr < 4; ++rr) {
                float p = __builtin_amdgcn_exp2f(sc[nt][rr] - mrow[rr]);
                rs[rr] += p;
                lds[pbase + swz(hi * 4 + rr, nt * 16 + lo)] = f2bf(p);
            }
        #pragma unroll
        for (int rr = 0; rr < 4; ++rr) lrow[rr] += red16_sum(rs[rr]);
        __builtin_amdgcn_s_setprio(1);
        #pragma unroll
        for (int dn = 0; dn < 4; ++dn)
            #pragma unroll
            for (int kc = 0; kc < 2; ++kc) {
                bf16x8 pfr = *(const bf16x8*)&lds[pbase + swz(lo, kc * 32 + hi * 8)];
                bf16x8 vfr = *(const bf16x8*)&lds[vA + swz(dn * 16 + lo, kc * 32 + hi * 8)];
                oacc[dn] = __builtin_amdgcn_mfma_f32_16x16x32_bf16(pfr, vfr, oacc[dn], 0, 0, 0);
            }
        __builtin_amdgcn_s_setprio(0);
        __syncthreads();
    }
    #pragma unroll
    for (int rr = 0; rr < 4; ++rr) {
        const float inv = 1.0f / lrow[rr];
        #pragma unroll
        for (int dn = 0; dn < 4; ++dn)
            Op[(size_t)(qrow0 + hi * 4 + rr) * D_DIM + dn * 16 + lo] = oacc[dn][rr] * inv;
    }
}

// ---- tier-3 fallback (no ws): reg-staged, fp32 inputs
__global__ __launch_bounds__(256, 4)
void attn_fb(const float* __restrict__ Qg, const float* __restrict__ Kg,
             const float* __restrict__ Vg, float* __restrict__ Og) {
    __shared__ __align__(16) unsigned short lds[20480];
    const int wg = blockIdx.x;
    const int x  = wg & 7;
    const int s  = (wg >> 3) & 31;
    const int r  = wg >> 8;
    const int bh = x * 4 + r;
    const int q  = (r & 1) ? (31 - s) : s;
    const int tid  = threadIdx.x;
    const int wid  = tid >> 6;
    const int lane = tid & 63;
    const int lo   = lane & 15;
    const int hi   = lane >> 4;
    const size_t boff = (size_t)bh * (S_LEN * D_DIM);
    const float* Qp = Qg + boff;
    const float* Kp = Kg + boff;
    const float* Vp = Vg + boff;
    float*       Op = Og + boff;
    const int qrow0 = q * 64 + wid * 16;
    bf16x8 qf[2];
    #pragma unroll
    for (int kc = 0; kc < 2; ++kc) {
        const float* src = Qp + (size_t)(qrow0 + lo) * D_DIM + kc * 32 + hi * 8;
        f32x4 a = *(const f32x4*)src;
        f32x4 b = *(const f32x4*)(src + 4);
        union { bf16x8 v; unsigned u[4]; } fr;
        fr.u[0] = pk2bf(a[0] * QS, a[1] * QS);
        fr.u[1] = pk2bf(a[2] * QS, a[3] * QS);
        fr.u[2] = pk2bf(b[0] * QS, b[1] * QS);
        fr.u[3] = pk2bf(b[2] * QS, b[3] * QS);
        qf[kc] = fr.v;
    }
    float mrow[4], lrow[4];
    f32x4 oacc[4];
    #pragma unroll
    for (int rr = 0; rr < 4; ++rr) { mrow[rr] = -INFINITY; lrow[rr] = 0.f; }
    #pragma unroll
    for (int dn = 0; dn < 4; ++dn) oacc[dn] = f32x4{0.f, 0.f, 0.f, 0.f};
    const int kr    = tid >> 2;
    const int kcb   = (tid & 3) << 4;
    const int vr    = (tid & 31) << 1;
    const int vcb   = (tid >> 5) << 3;
    const int pbase = 16384 + (wid << 10);
    const int T = q + 1;
    f32x4 kst[4], vst[4];
    {
        const float* ks = Kp + (size_t)kr * D_DIM + kcb;
        kst[0] = *(const f32x4*)ks;       kst[1] = *(const f32x4*)(ks + 4);
        kst[2] = *(const f32x4*)(ks + 8); kst[3] = *(const f32x4*)(ks + 12);
        const float* vs = Vp + (size_t)vr * D_DIM + vcb;
        vst[0] = *(const f32x4*)vs;           vst[1] = *(const f32x4*)(vs + 4);
        vst[2] = *(const f32x4*)(vs + D_DIM); vst[3] = *(const f32x4*)(vs + D_DIM + 4);
        union { uint4 w4; unsigned u[4]; } w;
        w.u[0] = pk2bf(kst[0][0], kst[0][1]); w.u[1] = pk2bf(kst[0][2], kst[0][3]);
        w.u[2] = pk2bf(kst[1][0], kst[1][1]); w.u[3] = pk2bf(kst[1][2], kst[1][3]);
        *(uint4*)&lds[swz(kr, kcb)] = w.w4;
        w.u[0] = pk2bf(kst[2][0], kst[2][1]); w.u[1] = pk2bf(kst[2][2], kst[2][3]);
        w.u[2] = pk2bf(kst[3][0], kst[3][1]); w.u[3] = pk2bf(kst[3][2], kst[3][3]);
        *(uint4*)&lds[swz(kr, kcb + 8)] = w.w4;
        #pragma unroll
        for (int cc = 0; cc < 8; ++cc) {
            unsigned pv = pk2bf(vst[cc >> 2][cc & 3], vst[2 + (cc >> 2)][cc & 3]);
            *(unsigned*)&lds[4096 + swz(vcb + cc, vr)] = pv;
        }
    }
    __syncthreads();
    for (int t = 0; t < T; ++t) {
        const int kA = (t & 1) << 13;
        const int vA = kA + 4096;
        const bool pf = (t + 1 < T);
        if (pf) {
            const int nb = (t + 1) * KVB;
            const float* ks = Kp + (size_t)(nb + kr) * D_DIM + kcb;
            kst[0] = *(const f32x4*)ks;       kst[1] = *(const f32x4*)(ks + 4);
            kst[2] = *(const f32x4*)(ks + 8); kst[3] = *(const f32x4*)(ks + 12);
            const float* vs = Vp + (size_t)(nb + vr) * D_DIM + vcb;
            vst[0] = *(const f32x4*)vs;           vst[1] = *(const f32x4*)(vs + 4);
            vst[2] = *(const f32x4*)(vs + D_DIM); vst[3] = *(const f32x4*)(vs + D_DIM + 4);
        }
        f32x4 sc[4];
        __builtin_amdgcn_s_setprio(1);
        #pragma unroll
        for (int nt = 0; nt < 4; ++nt) {
            f32x4 acc = f32x4{0.f, 0.f, 0.f, 0.f};
            #pragma unroll
            for (int kc = 0; kc < 2; ++kc) {
                bf16x8 kf = *(const bf16x8*)&lds[kA + swz(nt * 16 + lo, kc * 32 + hi * 8)];
                acc = __builtin_amdgcn_mfma_f32_16x16x32_bf16(qf[kc], kf, acc, 0, 0, 0);
            }
            sc[nt] = acc;
        }
        __builtin_amdgcn_s_setprio(0);
        if (t == q) {
            const int kb = t * KVB;
            #pragma unroll
            for (int nt = 0; nt < 4; ++nt)
                #pragma unroll
                for (int rr = 0; rr < 4; ++rr)
                    if (kb + nt * 16 + lo > qrow0 + hi * 4 + rr) sc[nt][rr] = -INFINITY;
        }
        float pm[4];
        #pragma unroll
        for (int rr = 0; rr < 4; ++rr)
            pm[rr] = red16_max(fmaxf(fmaxf(sc[0][rr], sc[1][rr]), fmaxf(sc[2][rr], sc[3][rr])));
        bool resc = false;
        #pragma unroll
        for (int rr = 0; rr < 4; ++rr) resc |= (pm[rr] > mrow[rr] + 8.f);
        if (__any(resc)) {
            #pragma unroll
            for (int rr = 0; rr < 4; ++rr) {
                const float mn = fmaxf(mrow[rr], pm[rr]);
                const float al = __builtin_amdgcn_exp2f(mrow[rr] - mn);
                mrow[rr] = mn;
                lrow[rr] *= al;
                #pragma unroll
                for (int dn = 0; dn < 4; ++dn) oacc[dn][rr] *= al;
            }
        }
        float rs[4] = {0.f, 0.f, 0.f, 0.f};
        #pragma unroll
        for (int nt = 0; nt < 4; ++nt)
            #pragma unroll
            for (int rr = 0; rr < 4; ++rr) {
                float p = __builtin_amdgcn_exp2f(sc[nt][rr] - mrow[rr]);
                rs[rr] += p;
                lds[pbase + swz(hi * 4 + rr, nt * 16 + lo)] = f2bf(p);
            }
        #pragma unroll
        for (int rr = 0; rr < 4; ++rr) lrow[rr] += red16_sum(rs[rr]);
        __builtin_amdgcn_s_setprio(1);
        #pragma unroll
        for (int dn = 0; dn < 4; ++dn)
            #pragma unroll
            for (int kc = 0; kc < 2; ++kc) {
                bf16x8 pfr = *(const bf16x8*)&lds[pbase + swz(lo, kc * 32 + hi * 8)];
                bf16x8 vfr = *(const bf16x8*)&lds[vA + swz(dn * 16 + lo, kc * 32 + hi * 8)];
                oacc[dn] = __builtin_amdgcn_mfma_f32_16x16x32_bf16(pfr, vfr, oacc[dn], 0, 0, 0);
            }
        __builtin_amdgcn_s_setprio(0);
        if (pf) {
            const int nA = ((t + 1) & 1) << 13;
            union { uint4 w4; unsigned u[4]; } w;
            w.u[0] = pk2bf(kst[0][0], kst[0][1]); w.u[1] = pk2bf(kst[0][2], kst[0][3]);
            w.u[2] = pk2bf(kst[1][0], kst[1][1]); w.u[3] = pk2bf(kst[1][2], kst[1][3]);
            *(uint4*)&lds[nA + swz(kr, kcb)] = w.w4;
            w.u[0] = pk2bf(kst[2][0], kst[2][1]); w.u[1] = pk2bf(kst[2][2], kst[2][3]);
            w.u[2] = pk2bf(kst[3][0], kst[3][1]); w.u[3] = pk2bf(kst[3][2], kst[3][3]);
            *(uint4*)&lds[nA + swz(kr, kcb + 8)] = w.w4;
            #pragma unroll
            for (int cc = 0; cc < 8; ++cc) {
                unsigned pv = pk2bf(vst[cc >> 2][cc & 3], vst[2 + (cc >> 2)][cc & 3]);
                *(unsigned*)&lds[nA + 4096 + swz(vcb + cc, vr)] = pv;
            }
        }
        __syncthreads();
    }
    #pragma unroll
    for (int rr = 0; rr < 4; ++rr) {
        const float inv = 1.0f / lrow[rr];
        #pragma unroll
        for (int dn = 0; dn < 4; ++dn)
            Op[(size_t)(qrow0 + hi * 4 + rr) * D_DIM + dn * 16 + lo] = oacc[dn][rr] * inv;
    }
}

extern "C" void kernel_launch(void* const* d_in, const int* in_sizes, int n_in,
                              void* d_out, int out_size, void* d_ws, size_t ws_size,
                              hipStream_t stream) {
    const float* Q = (const float*)d_in[0];
    const float* K = (const float*)d_in[1];
    const float* V = (const float*)d_in[2];
    float* O = (float*)d_out;
    const size_t prepBytes  = (size_t)32 * 131072 * 2 * sizeof(unsigned short);   // 16 MB
    const size_t splitBytes = prepBytes + (size_t)1024 * 4224 * sizeof(float);    // +17.3 MB
    unsigned short* wsK = (unsigned short*)d_ws;
    unsigned short* wsV = wsK + (size_t)32 * 131072;
    float*          wsP = (float*)(wsV + (size_t)32 * 131072);
    if (ws_size >= splitBytes) {
        prep_kv<<<dim3(1024), dim3(256), 0, stream>>>(K, V, wsK, wsV);
        attn_sp<<<dim3(1536), dim3(256), 0, stream>>>(Q, wsK, wsV, O, wsP);
        combine_k<<<dim3(512), dim3(256), 0, stream>>>(wsP, O);
    } else if (ws_size >= prepBytes) {
        prep_kv<<<dim3(1024), dim3(256), 0, stream>>>(K, V, wsK, wsV);
        attn_fast<<<dim3(1024), dim3(256), 0, stream>>>(Q, wsK, wsV, O);
    } else {
        attn_fb<<<dim3(1024), dim3(256), 0, stream>>>(Q, K, V, O);
    }
}